// Round 7
// baseline (318.111 us; speedup 1.0000x reference)
//
#include <hip/hip_runtime.h>
#include <hip/hip_bf16.h>

// out[m,b,:] = kv[m,b,:] @ W + bo + query[b,:],  W = (Wo@Wv) row o, col d
// (softmax over size-1 axis == 1 -> ones; q/k/Wq/Wk dead).
// OUTPUT DTYPE IS FLOAT32 (reference returns f32; out_npz=124MB == compressed
// 134MB f32, not 67MB bf16). Rounds 1-6 failed solely on storing bf16 shorts.
// K1: Cw[o][d] = sum_e Wo[o][e]*Wv[e][d], f32 accum, bf16 store in d_ws (proven).
// K2: out[r][o] = sum_d kv[r][d]*Cw[o][d] + bo[o] + query[r&4095][o], f32 out.

typedef __attribute__((ext_vector_type(4))) float f32x4;
typedef __attribute__((ext_vector_type(8))) short short8;

#define D_MODEL 1024
#define BATCH   4096
#define M_ROWS  32768   // 8 * 4096

__device__ __forceinline__ short f2bf(float f) {
    union { float f; unsigned u; } x; x.f = f;
    unsigned r = (x.u + 0x7fffu + ((x.u >> 16) & 1u)) >> 16;   // RNE
    return (short)r;
}

__device__ __forceinline__ short8 cvt8(float4 a, float4 b) {
    short8 s;
    s[0] = f2bf(a.x); s[1] = f2bf(a.y); s[2] = f2bf(a.z); s[3] = f2bf(a.w);
    s[4] = f2bf(b.x); s[5] = f2bf(b.y); s[6] = f2bf(b.z); s[7] = f2bf(b.w);
    return s;
}

// ---------------- Kernel 1: simple Cw = Wo @ Wv (f32 math, bf16 store) ----------------
// 128 blocks x 512 threads; block handles 8 o-rows; thread t owns d = {2t, 2t+1}.
__global__ __launch_bounds__(512) void fuse_w_simple(
        const float* __restrict__ Wo, const float* __restrict__ Wv,
        short* __restrict__ Cw) {
    __shared__ float wo[8][D_MODEL];               // 32 KB
    const int t = threadIdx.x;
    const int ob = blockIdx.x * 8;
#pragma unroll
    for (int j = 0; j < 4; ++j) {
        int lin = j * 512 + t;
        int row = lin >> 8, c = lin & 255;
        *(float4*)&wo[row][c * 4] =
            *(const float4*)(Wo + (size_t)(ob + row) * D_MODEL + c * 4);
    }
    __syncthreads();
    float acc[8][2] = {};
    for (int e = 0; e < D_MODEL; ++e) {
        float2 v = *(const float2*)(Wv + (size_t)e * D_MODEL + t * 2);
#pragma unroll
        for (int r = 0; r < 8; ++r) {
            float w = wo[r][e];
            acc[r][0] += w * v.x;
            acc[r][1] += w * v.y;
        }
    }
#pragma unroll
    for (int r = 0; r < 8; ++r) {
        Cw[(size_t)(ob + r) * D_MODEL + t * 2 + 0] = f2bf(acc[r][0]);
        Cw[(size_t)(ob + r) * D_MODEL + t * 2 + 1] = f2bf(acc[r][1]);
    }
}

// ---------------- Kernel 2: out = kv @ Cw.T + bo + query (residual), f32 out ----------------
__global__ __launch_bounds__(256) void attn_gemm_kernel(
        const float* __restrict__ kv, const float* __restrict__ query,
        const short* __restrict__ Cw, const float* __restrict__ bo,
        float* __restrict__ out) {
    __shared__ __align__(16) short Ash[128][32];   // kv tile (bf16)  [row][d]
    __shared__ __align__(16) short Bsh[128][32];   // Cw tile         [o][d]
    const int t = threadIdx.x;
    const int lane = t & 63;
    const int w = t >> 6;
    const int wr = w >> 1, wc = w & 1;
    const int bx = blockIdx.x;              // o-tile (0..7)
    const int brow = blockIdx.y * 128;      // global row tile

    f32x4 acc[4][4];
#pragma unroll
    for (int m = 0; m < 4; ++m)
#pragma unroll
        for (int n = 0; n < 4; ++n) acc[m][n] = (f32x4)(0.0f);

    for (int kt = 0; kt < 32; ++kt) {
        // A: load f32 kv chunks to regs (coalesced 32B/thread)
        float4 av[2][2];
#pragma unroll
        for (int j = 0; j < 2; ++j) {
            int lin = j * 256 + t;
            int row = lin >> 2, blk = lin & 3;
            const float* g = kv + (size_t)(brow + row) * D_MODEL + kt * 32 + blk * 8;
            av[j][0] = *(const float4*)g;
            av[j][1] = *(const float4*)(g + 4);
        }
        // B: bf16 W tile direct global->LDS (16B per lane per issue)
#pragma unroll
        for (int i = 0; i < 2; ++i) {
            int lin = i * 256 + t;
            int row = lin >> 2, c8 = lin & 3;
            const short* g = Cw + (size_t)(bx * 128 + row) * D_MODEL + kt * 32 + c8 * 8;
            __builtin_amdgcn_global_load_lds(
                (const __attribute__((address_space(1))) void*)g,
                (__attribute__((address_space(3))) void*)((char*)&Bsh[0][0] + i * 4096 + w * 1024),
                16, 0, 0);
        }
        // A: convert + LDS write (bf16)
#pragma unroll
        for (int j = 0; j < 2; ++j) {
            int lin = j * 256 + t;
            int row = lin >> 2, blk = lin & 3;
            *reinterpret_cast<short8*>(&Ash[row][blk * 8]) = cvt8(av[j][0], av[j][1]);
        }
        __syncthreads();
        {
            const int r = lane & 15, q = lane >> 4;
            short8 af[4], bfr[4];
#pragma unroll
            for (int m = 0; m < 4; ++m)
                af[m] = *reinterpret_cast<const short8*>(&Ash[wr * 64 + m * 16 + r][q * 8]);
#pragma unroll
            for (int n = 0; n < 4; ++n)
                bfr[n] = *reinterpret_cast<const short8*>(&Bsh[wc * 64 + n * 16 + r][q * 8]);
#pragma unroll
            for (int m = 0; m < 4; ++m)
#pragma unroll
                for (int n = 0; n < 4; ++n)
                    acc[m][n] = __builtin_amdgcn_mfma_f32_16x16x32_bf16(
                        af[m], bfr[n], acc[m][n], 0, 0, 0);
        }
        __syncthreads();
    }

    // epilogue: + bo + query residual, f32 store
    const int r = lane & 15, q = lane >> 4;
#pragma unroll
    for (int n = 0; n < 4; ++n) {
        int o = bx * 128 + wc * 64 + n * 16 + r;
        float bov = bo[o];
#pragma unroll
        for (int m = 0; m < 4; ++m) {
            int gb = brow + wr * 64 + m * 16 + q * 4;
#pragma unroll
            for (int j = 0; j < 4; ++j) {
                int grow = gb + j;
                out[(size_t)grow * D_MODEL + o] =
                    acc[m][n][j] + bov +
                    query[(size_t)(grow & (BATCH - 1)) * D_MODEL + o];
            }
        }
    }
}

extern "C" void kernel_launch(void* const* d_in, const int* in_sizes, int n_in,
                              void* d_out, int out_size, void* d_ws, size_t ws_size,
                              hipStream_t stream) {
    // Robust input classification by element count (falls back to dict order):
    int kv_i = 1, q_i = 0, bo_i = 6;
    int w_i[4] = {2, 3, 4, 5};
    int nw = 0;
    for (int i = 0; i < n_in; ++i) {
        long s = in_sizes[i];
        if (s == 33554432) kv_i = i;
        else if (s == 4194304) q_i = i;
        else if (s == 1024) bo_i = i;
        else if (s == 1048576 && nw < 4) w_i[nw++] = i;
    }
    const float* query = (const float*)d_in[q_i];
    const float* kv    = (const float*)d_in[kv_i];
    const float* Wv    = (const float*)d_in[w_i[2]];
    const float* Wo    = (const float*)d_in[w_i[3]];
    const float* bo    = (const float*)d_in[bo_i];
    short* Cw  = (short*)d_ws;              // 1024*1024 bf16 = 2 MB
    float* out = (float*)d_out;             // f32 output

    fuse_w_simple<<<dim3(128), dim3(512), 0, stream>>>(Wo, Wv, Cw);
    attn_gemm_kernel<<<dim3(8, M_ROWS / 128), dim3(256), 0, stream>>>(kv, query, Cw, bo, out);
}

// Round 8
// 283.119 us; speedup vs baseline: 1.1236x; 1.1236x over previous
//
#include <hip/hip_runtime.h>
#include <hip/hip_bf16.h>

// out[m,b,:] = kv[m,b,:] @ W + bo + query[b,:],  W = (Wo@Wv) row o, col d
// (softmax over size-1 axis == 1 -> ones; q/k/Wq/Wk dead). f32 output.
// K1: Cw[o][d] = sum_e Wo[o][e]*Wv[e][d], MFMA bf16, ~10us (r3-fixed staging).
// K2: out[r][o] = sum_d kv[r][d]*Cw[o][d] + bo[o] + query[r&4095][o].
//     1-D grid + XCD-swizzle: 8 o-blocks of a row-tile share L%8 -> same XCD
//     -> kv tile L2-reused 8x (fetch 574 MB -> ~180 MB predicted).

typedef __attribute__((ext_vector_type(4))) float f32x4;
typedef __attribute__((ext_vector_type(8))) short short8;

#define D_MODEL 1024
#define BATCH   4096
#define M_ROWS  32768   // 8 * 4096

__device__ __forceinline__ short f2bf(float f) {
    union { float f; unsigned u; } x; x.f = f;
    unsigned r = (x.u + 0x7fffu + ((x.u >> 16) & 1u)) >> 16;   // RNE
    return (short)r;
}

__device__ __forceinline__ short8 cvt8(float4 a, float4 b) {
    short8 s;
    s[0] = f2bf(a.x); s[1] = f2bf(a.y); s[2] = f2bf(a.z); s[3] = f2bf(a.w);
    s[4] = f2bf(b.x); s[5] = f2bf(b.y); s[6] = f2bf(b.z); s[7] = f2bf(b.w);
    return s;
}

// ---------------- Kernel 1: fuse weights: Cw = Wo @ Wv (bf16, MFMA) ----------------
__global__ __launch_bounds__(256) void fuse_w_kernel(
        const float* __restrict__ Wo, const float* __restrict__ Wv,
        short* __restrict__ Cw) {
    __shared__ __align__(16) short Ash[128][32];   // Wo tile  [o][e]
    __shared__ __align__(16) short Bsh[128][32];   // Wv tile transposed: [d][e]
    const int t = threadIdx.x;
    const int lane = t & 63;
    const int w = t >> 6;
    const int wr = w >> 1, wc = w & 1;
    const int brow = blockIdx.y * 128;   // o
    const int bcol = blockIdx.x * 128;   // d

    f32x4 acc[4][4];
#pragma unroll
    for (int m = 0; m < 4; ++m)
#pragma unroll
        for (int n = 0; n < 4; ++n) acc[m][n] = (f32x4)(0.0f);

    for (int kt = 0; kt < 32; ++kt) {
        float4 av[2][2];
#pragma unroll
        for (int j = 0; j < 2; ++j) {
            int lin = j * 256 + t;              // 512 chunks of 8 f32 (128 rows x 4 blks)
            int row = lin >> 2, blk = lin & 3;
            const float* g = Wo + (size_t)(brow + row) * D_MODEL + kt * 32 + blk * 8;
            av[j][0] = *(const float4*)g;
            av[j][1] = *(const float4*)(g + 4);
        }
        // B tile: 32 rows (e) x 128 cols (d) = 1024 float4 (4/thread)
        float4 bv[4];
#pragma unroll
        for (int j = 0; j < 4; ++j) {
            int lin = j * 256 + t;
            int e = lin >> 5, c4 = lin & 31;
            bv[j] = *(const float4*)(Wv + (size_t)(kt * 32 + e) * D_MODEL + bcol + c4 * 4);
        }
#pragma unroll
        for (int j = 0; j < 2; ++j) {
            int lin = j * 256 + t;
            int row = lin >> 2, blk = lin & 3;
            *reinterpret_cast<short8*>(&Ash[row][blk * 8]) = cvt8(av[j][0], av[j][1]);
        }
#pragma unroll
        for (int j = 0; j < 4; ++j) {
            int lin = j * 256 + t;
            int e = lin >> 5, c4 = lin & 31;
            int d = c4 * 4;
            Bsh[d + 0][e] = f2bf(bv[j].x);
            Bsh[d + 1][e] = f2bf(bv[j].y);
            Bsh[d + 2][e] = f2bf(bv[j].z);
            Bsh[d + 3][e] = f2bf(bv[j].w);
        }
        __syncthreads();
        {
            const int r = lane & 15, q = lane >> 4;
            short8 af[4], bfr[4];
#pragma unroll
            for (int m = 0; m < 4; ++m)
                af[m] = *reinterpret_cast<const short8*>(&Ash[wr * 64 + m * 16 + r][q * 8]);
#pragma unroll
            for (int n = 0; n < 4; ++n)
                bfr[n] = *reinterpret_cast<const short8*>(&Bsh[wc * 64 + n * 16 + r][q * 8]);
#pragma unroll
            for (int m = 0; m < 4; ++m)
#pragma unroll
                for (int n = 0; n < 4; ++n)
                    acc[m][n] = __builtin_amdgcn_mfma_f32_16x16x32_bf16(
                        af[m], bfr[n], acc[m][n], 0, 0, 0);
        }
        __syncthreads();
    }

    const int r = lane & 15, q = lane >> 4;
#pragma unroll
    for (int m = 0; m < 4; ++m)
#pragma unroll
        for (int n = 0; n < 4; ++n)
#pragma unroll
            for (int j = 0; j < 4; ++j) {
                int o = brow + wr * 64 + m * 16 + q * 4 + j;     // C/D: row=(l>>4)*4+j
                int d = bcol + wc * 64 + n * 16 + r;             //      col=l&15
                Cw[(size_t)o * D_MODEL + d] = f2bf(acc[m][n][j]);
            }
}

// ---------------- Kernel 2: out = kv @ Cw.T + bo + query (residual), f32 out ----------------
__global__ __launch_bounds__(256) void attn_gemm_kernel(
        const float* __restrict__ kv, const float* __restrict__ query,
        const short* __restrict__ Cw, const float* __restrict__ bo,
        float* __restrict__ out) {
    __shared__ __align__(16) short Ash[128][32];   // kv tile (bf16)  [row][d]
    __shared__ __align__(16) short Bsh[128][32];   // Cw tile         [o][d]
    const int t = threadIdx.x;
    const int lane = t & 63;
    const int w = t >> 6;
    const int wr = w >> 1, wc = w & 1;

    // XCD swizzle: XCD = L % 8 (round-robin). Put all 8 o-tiles of one
    // row-tile on the SAME XCD, <=64 dispatch slots apart -> kv L2 reuse.
    const int L = blockIdx.x;
    const int x = L & 7, j5 = L >> 3;
    const int bx = j5 & 7;                   // o-tile (0..7)
    const int rt = (j5 >> 3) * 8 + x;        // row-tile (0..255)
    const int brow = rt * 128;

    f32x4 acc[4][4];
#pragma unroll
    for (int m = 0; m < 4; ++m)
#pragma unroll
        for (int n = 0; n < 4; ++n) acc[m][n] = (f32x4)(0.0f);

    for (int kt = 0; kt < 32; ++kt) {
        // A: load f32 kv chunks to regs (coalesced 32B/thread)
        float4 av[2][2];
#pragma unroll
        for (int j = 0; j < 2; ++j) {
            int lin = j * 256 + t;
            int row = lin >> 2, blk = lin & 3;
            const float* g = kv + (size_t)(brow + row) * D_MODEL + kt * 32 + blk * 8;
            av[j][0] = *(const float4*)g;
            av[j][1] = *(const float4*)(g + 4);
        }
        // B: bf16 W tile direct global->LDS (16B per lane per issue)
#pragma unroll
        for (int i = 0; i < 2; ++i) {
            int lin = i * 256 + t;
            int row = lin >> 2, c8 = lin & 3;
            const short* g = Cw + (size_t)(bx * 128 + row) * D_MODEL + kt * 32 + c8 * 8;
            __builtin_amdgcn_global_load_lds(
                (const __attribute__((address_space(1))) void*)g,
                (__attribute__((address_space(3))) void*)((char*)&Bsh[0][0] + i * 4096 + w * 1024),
                16, 0, 0);
        }
        // A: convert + LDS write (bf16)
#pragma unroll
        for (int j = 0; j < 2; ++j) {
            int lin = j * 256 + t;
            int row = lin >> 2, blk = lin & 3;
            *reinterpret_cast<short8*>(&Ash[row][blk * 8]) = cvt8(av[j][0], av[j][1]);
        }
        __syncthreads();
        {
            const int r = lane & 15, q = lane >> 4;
            short8 af[4], bfr[4];
#pragma unroll
            for (int m = 0; m < 4; ++m)
                af[m] = *reinterpret_cast<const short8*>(&Ash[wr * 64 + m * 16 + r][q * 8]);
#pragma unroll
            for (int n = 0; n < 4; ++n)
                bfr[n] = *reinterpret_cast<const short8*>(&Bsh[wc * 64 + n * 16 + r][q * 8]);
#pragma unroll
            for (int m = 0; m < 4; ++m)
#pragma unroll
                for (int n = 0; n < 4; ++n)
                    acc[m][n] = __builtin_amdgcn_mfma_f32_16x16x32_bf16(
                        af[m], bfr[n], acc[m][n], 0, 0, 0);
        }
        __syncthreads();
    }

    // epilogue: + bo + query residual, f32 store
    const int r = lane & 15, q = lane >> 4;
#pragma unroll
    for (int n = 0; n < 4; ++n) {
        int o = bx * 128 + wc * 64 + n * 16 + r;
        float bov = bo[o];
#pragma unroll
        for (int m = 0; m < 4; ++m) {
            int gb = brow + wr * 64 + m * 16 + q * 4;
#pragma unroll
            for (int j = 0; j < 4; ++j) {
                int grow = gb + j;
                out[(size_t)grow * D_MODEL + o] =
                    acc[m][n][j] + bov +
                    query[(size_t)(grow & (BATCH - 1)) * D_MODEL + o];
            }
        }
    }
}

extern "C" void kernel_launch(void* const* d_in, const int* in_sizes, int n_in,
                              void* d_out, int out_size, void* d_ws, size_t ws_size,
                              hipStream_t stream) {
    // Robust input classification by element count (falls back to dict order):
    int kv_i = 1, q_i = 0, bo_i = 6;
    int w_i[4] = {2, 3, 4, 5};
    int nw = 0;
    for (int i = 0; i < n_in; ++i) {
        long s = in_sizes[i];
        if (s == 33554432) kv_i = i;
        else if (s == 4194304) q_i = i;
        else if (s == 1024) bo_i = i;
        else if (s == 1048576 && nw < 4) w_i[nw++] = i;
    }
    const float* query = (const float*)d_in[q_i];
    const float* kv    = (const float*)d_in[kv_i];
    const float* Wv    = (const float*)d_in[w_i[2]];
    const float* Wo    = (const float*)d_in[w_i[3]];
    const float* bo    = (const float*)d_in[bo_i];
    short* Cw  = (short*)d_ws;              // 1024*1024 bf16 = 2 MB
    float* out = (float*)d_out;             // f32 output

    fuse_w_kernel<<<dim3(8, 8), dim3(256), 0, stream>>>(Wo, Wv, Cw);
    attn_gemm_kernel<<<dim3(2048), dim3(256), 0, stream>>>(kv, query, Cw, bo, out);
}

// Round 9
// 212.265 us; speedup vs baseline: 1.4986x; 1.3338x over previous
//
#include <hip/hip_runtime.h>
#include <hip/hip_bf16.h>

// out[m,b,:] = kv[m,b,:] @ W + bo + query[b,:],  W = (Wo@Wv) row o, col d
// (softmax over size-1 axis == 1 -> ones; q/k/Wq/Wk dead). f32 output.
// K1: Cw[o][d] = sum_e Wo[o][e]*Wv[e][d], MFMA bf16, 64x64 tiles, 256 blocks.
// K2: out[r][o] = sum_d kv[r][d]*Cw[o][d] + bo[o] + query[r&4095][o].
//     2-phase double-buffered: next-tile A-reg loads + B-glds issued BEFORE
//     compute of current tile; cvt+ds_write after MFMAs; 1 barrier/K-step.
//     XCD swizzle kept (FETCH 574->141 MB proven in r8).

typedef __attribute__((ext_vector_type(4))) float f32x4;
typedef __attribute__((ext_vector_type(8))) short short8;

#define D_MODEL 1024
#define BATCH   4096
#define M_ROWS  32768   // 8 * 4096

__device__ __forceinline__ short f2bf(float f) {
    union { float f; unsigned u; } x; x.f = f;
    unsigned r = (x.u + 0x7fffu + ((x.u >> 16) & 1u)) >> 16;   // RNE
    return (short)r;
}

__device__ __forceinline__ unsigned bfpk(float lo, float hi) {
    __hip_bfloat162 h = __float22bfloat162_rn(make_float2(lo, hi));  // v_cvt_pk_bf16_f32
    unsigned u; __builtin_memcpy(&u, &h, 4); return u;
}

__device__ __forceinline__ short8 cvt8(float4 a, float4 b) {
    union { unsigned u[4]; short8 s; } r;
    r.u[0] = bfpk(a.x, a.y);
    r.u[1] = bfpk(a.z, a.w);
    r.u[2] = bfpk(b.x, b.y);
    r.u[3] = bfpk(b.z, b.w);
    return r.s;
}

// ---------------- Kernel 1: fuse weights Cw = Wo @ Wv (bf16, MFMA, 64x64) ----------------
__global__ __launch_bounds__(256) void fuse_w_kernel(
        const float* __restrict__ Wo, const float* __restrict__ Wv,
        short* __restrict__ Cw) {
    __shared__ __align__(16) short Ash[64][32];   // Wo tile  [o][e]
    __shared__ __align__(16) short Bsh[64][32];   // Wv tile transposed: [d][e]
    const int t = threadIdx.x;
    const int lane = t & 63;
    const int w = t >> 6;
    const int wr = w >> 1, wc = w & 1;
    const int brow = blockIdx.y * 64;   // o
    const int bcol = blockIdx.x * 64;   // d

    f32x4 acc[2][2];
#pragma unroll
    for (int m = 0; m < 2; ++m)
#pragma unroll
        for (int n = 0; n < 2; ++n) acc[m][n] = (f32x4)(0.0f);

    for (int kt = 0; kt < 32; ++kt) {
        // A: 64 rows x 32 e = 2048 f32; thread: row=t>>2, blk=t&3 (8 floats)
        const float* ga = Wo + (size_t)(brow + (t >> 2)) * D_MODEL + kt * 32 + (t & 3) * 8;
        float4 a0 = *(const float4*)ga;
        float4 a1 = *(const float4*)(ga + 4);
        // B: Wv[e][d] 32 x 64 = 2048 f32; 512 float4: e=lin>>4, c4=lin&15
        float4 bv[2];
#pragma unroll
        for (int j = 0; j < 2; ++j) {
            int lin = j * 256 + t;
            int e = lin >> 4, c4 = lin & 15;
            bv[j] = *(const float4*)(Wv + (size_t)(kt * 32 + e) * D_MODEL + bcol + c4 * 4);
        }
        *reinterpret_cast<short8*>(&Ash[t >> 2][(t & 3) * 8]) = cvt8(a0, a1);
#pragma unroll
        for (int j = 0; j < 2; ++j) {
            int lin = j * 256 + t;
            int e = lin >> 4, c4 = lin & 15;
            int d = c4 * 4;
            Bsh[d + 0][e] = f2bf(bv[j].x);
            Bsh[d + 1][e] = f2bf(bv[j].y);
            Bsh[d + 2][e] = f2bf(bv[j].z);
            Bsh[d + 3][e] = f2bf(bv[j].w);
        }
        __syncthreads();
        {
            const int r = lane & 15, q = lane >> 4;
            short8 af[2], bfr[2];
#pragma unroll
            for (int m = 0; m < 2; ++m)
                af[m] = *reinterpret_cast<const short8*>(&Ash[wr * 32 + m * 16 + r][q * 8]);
#pragma unroll
            for (int n = 0; n < 2; ++n)
                bfr[n] = *reinterpret_cast<const short8*>(&Bsh[wc * 32 + n * 16 + r][q * 8]);
#pragma unroll
            for (int m = 0; m < 2; ++m)
#pragma unroll
                for (int n = 0; n < 2; ++n)
                    acc[m][n] = __builtin_amdgcn_mfma_f32_16x16x32_bf16(
                        af[m], bfr[n], acc[m][n], 0, 0, 0);
        }
        __syncthreads();
    }

    const int r = lane & 15, q = lane >> 4;
#pragma unroll
    for (int m = 0; m < 2; ++m)
#pragma unroll
        for (int n = 0; n < 2; ++n)
#pragma unroll
            for (int j = 0; j < 4; ++j) {
                int o = brow + wr * 32 + m * 16 + q * 4 + j;     // C/D: row=(l>>4)*4+j
                int d = bcol + wc * 32 + n * 16 + r;             //      col=l&15
                Cw[(size_t)o * D_MODEL + d] = f2bf(acc[m][n][j]);
            }
}

// ---------------- Kernel 2: out = kv @ Cw.T + bo + query, 2-phase pipelined ----------------
struct AV { float4 v[2][2]; };

__global__ __launch_bounds__(256) void attn_gemm_kernel(
        const float* __restrict__ kv, const float* __restrict__ query,
        const short* __restrict__ Cw, const float* __restrict__ bo,
        float* __restrict__ out) {
    __shared__ __align__(16) short Ash[2][128][32];   // kv tile (bf16), double-buffered
    __shared__ __align__(16) short Bsh[2][128][32];   // Cw tile, double-buffered
    const int t = threadIdx.x;
    const int lane = t & 63;
    const int w = t >> 6;
    const int wr = w >> 1, wc = w & 1;

    // XCD swizzle: XCD = L % 8. All 8 o-tiles of one row-tile share L%8 ->
    // same XCD, co-resident -> kv L2-reused 8x (proven r8: FETCH 574->141 MB).
    const int L = blockIdx.x;
    const int x = L & 7, j5 = L >> 3;
    const int bx = j5 & 7;                   // o-tile (0..7)
    const int rt = (j5 >> 3) * 8 + x;        // row-tile (0..255)
    const int brow = rt * 128;

    f32x4 acc[4][4];
#pragma unroll
    for (int m = 0; m < 4; ++m)
#pragma unroll
        for (int n = 0; n < 4; ++n) acc[m][n] = (f32x4)(0.0f);

    auto load_a = [&](int kt) {
        AV a;
#pragma unroll
        for (int j = 0; j < 2; ++j) {
            const float* g = kv + (size_t)(brow + j * 64 + (t >> 2)) * D_MODEL
                             + kt * 32 + (t & 3) * 8;
            a.v[j][0] = *(const float4*)g;
            a.v[j][1] = *(const float4*)(g + 4);
        }
        return a;
    };
    auto stage_b = [&](int kt, int buf) {
#pragma unroll
        for (int i = 0; i < 2; ++i) {
            const short* g = Cw + (size_t)(bx * 128 + i * 64 + (t >> 2)) * D_MODEL
                             + kt * 32 + (t & 3) * 8;
            __builtin_amdgcn_global_load_lds(
                (const __attribute__((address_space(1))) void*)g,
                (__attribute__((address_space(3))) void*)
                    ((char*)&Bsh[buf][0][0] + i * 4096 + w * 1024),
                16, 0, 0);
        }
    };
    auto write_a = [&](int buf, const AV& a) {
#pragma unroll
        for (int j = 0; j < 2; ++j)
            *reinterpret_cast<short8*>(&Ash[buf][j * 64 + (t >> 2)][(t & 3) * 8]) =
                cvt8(a.v[j][0], a.v[j][1]);
    };
    auto compute = [&](int buf) {
        const int r = lane & 15, q = lane >> 4;
        short8 af[4], bfr[4];
#pragma unroll
        for (int m = 0; m < 4; ++m)
            af[m] = *reinterpret_cast<const short8*>(&Ash[buf][wr * 64 + m * 16 + r][q * 8]);
#pragma unroll
        for (int n = 0; n < 4; ++n)
            bfr[n] = *reinterpret_cast<const short8*>(&Bsh[buf][wc * 64 + n * 16 + r][q * 8]);
#pragma unroll
        for (int m = 0; m < 4; ++m)
#pragma unroll
            for (int n = 0; n < 4; ++n)
                acc[m][n] = __builtin_amdgcn_mfma_f32_16x16x32_bf16(
                    af[m], bfr[n], acc[m][n], 0, 0, 0);
    };

    // prologue: stage tile 0 into buf 0
    AV a = load_a(0);
    stage_b(0, 0);
    write_a(0, a);
    __syncthreads();

#pragma unroll 2
    for (int kt = 0; kt < 32; ++kt) {
        const int cur = kt & 1;
        if (kt < 31) {                 // issue next tile early (latency hides
            a = load_a(kt + 1);        //  under ds_read+MFMA below)
            stage_b(kt + 1, cur ^ 1);
        }
        compute(cur);
        if (kt < 31) write_a(cur ^ 1, a);   // waits loads, converts, writes
        __syncthreads();               // one barrier per K-step
    }

    // epilogue: + bo + query residual, f32 store
    const int r = lane & 15, q = lane >> 4;
#pragma unroll
    for (int n = 0; n < 4; ++n) {
        int o = bx * 128 + wc * 64 + n * 16 + r;
        float bov = bo[o];
#pragma unroll
        for (int m = 0; m < 4; ++m) {
            int gb = brow + wr * 64 + m * 16 + q * 4;
#pragma unroll
            for (int j = 0; j < 4; ++j) {
                int grow = gb + j;
                out[(size_t)grow * D_MODEL + o] =
                    acc[m][n][j] + bov +
                    query[(size_t)(grow & (BATCH - 1)) * D_MODEL + o];
            }
        }
    }
}

extern "C" void kernel_launch(void* const* d_in, const int* in_sizes, int n_in,
                              void* d_out, int out_size, void* d_ws, size_t ws_size,
                              hipStream_t stream) {
    // Robust input classification by element count (falls back to dict order):
    int kv_i = 1, q_i = 0, bo_i = 6;
    int w_i[4] = {2, 3, 4, 5};
    int nw = 0;
    for (int i = 0; i < n_in; ++i) {
        long s = in_sizes[i];
        if (s == 33554432) kv_i = i;
        else if (s == 4194304) q_i = i;
        else if (s == 1024) bo_i = i;
        else if (s == 1048576 && nw < 4) w_i[nw++] = i;
    }
    const float* query = (const float*)d_in[q_i];
    const float* kv    = (const float*)d_in[kv_i];
    const float* Wv    = (const float*)d_in[w_i[2]];
    const float* Wo    = (const float*)d_in[w_i[3]];
    const float* bo    = (const float*)d_in[bo_i];
    short* Cw  = (short*)d_ws;              // 1024*1024 bf16 = 2 MB
    float* out = (float*)d_out;             // f32 output

    fuse_w_kernel<<<dim3(16, 16), dim3(256), 0, stream>>>(Wo, Wv, Cw);
    attn_gemm_kernel<<<dim3(2048), dim3(256), 0, stream>>>(kv, query, Cw, bo, out);
}